// Round 2
// baseline (719.374 us; speedup 1.0000x reference)
//
#include <hip/hip_runtime.h>
#include <cstdint>
#include <cstddef>

#define BT_TOT 64000
#define FIN    1024
#define GV     640
#define NV     320
#define VD     128
#define INV_BT (1.0f/64000.0f)

// K-tile = 16 (one k-chunk per 32x32x16 MFMA). 64 K-steps.
// Packed W tile (per kt): [s(hi/lo)][col 0..639][chunk 0..1][8 bf16] = 40960 B
#define WTILE_B 40960

typedef __attribute__((ext_vector_type(8))) __bf16 bf16x8;
typedef __attribute__((ext_vector_type(16))) float f32x16;

typedef __attribute__((address_space(1))) void gvoid_t;
typedef __attribute__((address_space(3))) void lvoid_t;

__device__ inline short f2bf(float x) {            // RNE fp32 -> bf16 bits
    unsigned int u = __float_as_uint(x);
    unsigned int r = (u + 0x7fffu + ((u >> 16) & 1u)) >> 16;
    return (short)r;
}
__device__ inline float bf2f(short h) {
    return __uint_as_float(((unsigned int)(unsigned short)h) << 16);
}
__device__ inline bf16x8 ld_frag(const short* p) {
    union { uint4 u; bf16x8 v; } t;
    t.u = *(const uint4*)p;
    return t.v;
}
__device__ __forceinline__ void glds16(const void* g, void* l) {
    __builtin_amdgcn_global_load_lds((gvoid_t*)g, (lvoid_t*)l, 16, 0, 0);
}

// ---------- prep: split W into bf16 hi/lo, packed per-K-tile in LDS order ----------
__global__ __launch_bounds__(256) void prep(
    const float* __restrict__ W, char* __restrict__ Wpk,
    float* __restrict__ psum_g, int* __restrict__ cnt_g)
{
    const int t = blockIdx.x * 256 + threadIdx.x;
    if (t < GV) { psum_g[t] = 0.f; cnt_g[t] = 0; }
    const int r   = t >> 7;        // row 0..639
    const int ck8 = t & 127;       // which 8-elem chunk along k
    const int kt  = ck8 >> 1;      // K-tile 0..63
    const int ch  = ck8 & 1;       // chunk within tile (0/1)
    const float* src = W + (size_t)r * FIN + (size_t)ck8 * 8;
    const float4 a = ((const float4*)src)[0];
    const float4 b = ((const float4*)src)[1];
    float xs[8] = {a.x, a.y, a.z, a.w, b.x, b.y, b.z, b.w};
    short hi[8], lo[8];
#pragma unroll
    for (int e = 0; e < 8; ++e) {
        hi[e] = f2bf(xs[e]);
        lo[e] = f2bf(xs[e] - bf2f(hi[e]));
    }
    char* dst = Wpk + (size_t)kt * WTILE_B + (size_t)r * 32 + ch * 16;
    *(uint4*)dst             = *(uint4*)hi;   // s=0 (hi)
    *(uint4*)(dst + 20480)   = *(uint4*)lo;   // s=1 (lo)
}

// ---------- fused: 32x32x16 bf16-triple GEMM, counted-vmcnt pipeline + epilogue ----------
// 500 blocks x 512 thr. Block = 128 rows x 640 cols. 8 waves: mw=wave&3 (32-row
// stripe), nw=wave>>2 (group, 320 cols). Wave tile 32x320 = 10 x (32x32), acc 160.
// A operand loaded global->reg (32 B/lane), only W staged in LDS (2 x 40 KB dbuf).
__global__ __launch_bounds__(512, 2) void fused(
    const float* __restrict__ X, const char* __restrict__ Wpk,
    const float* __restrict__ bias, const float* __restrict__ gumbel,
    const float* __restrict__ codebook, float* __restrict__ q,
    float* __restrict__ psum_g, int* __restrict__ cnt_g)
{
    __shared__ __align__(16) char smem[2 * WTILE_B];   // 80 KB

    const int tid  = threadIdx.x;
    const int lane = tid & 63, wave = tid >> 6;
    const int mw = wave & 3, nw = wave >> 2;
    const int cl = lane & 31, h = lane >> 5;
    const int row0 = blockIdx.x * 128;
    const int arow = mw * 32 + cl;                    // A row this lane owns

    f32x16 acc[10];
#pragma unroll
    for (int nt = 0; nt < 10; ++nt) acc[nt] = (f32x16)0.0f;

    const float* aptr = X + (size_t)(row0 + arow) * FIN + h * 8;

    // ---- prologue: stage K-tile 0 (W -> buf0, A(0) -> regs) ----
    float4 xa0, xa1;
    {
#pragma unroll
        for (int i = 0; i < 5; ++i) {
            const int task = tid + 512 * i;
            glds16(Wpk + (size_t)task * 16, smem + task * 16);
        }
        __builtin_amdgcn_sched_barrier(0);
        xa0 = *(const float4*)(aptr);
        xa1 = *(const float4*)(aptr + 4);
    }

    // ---- main loop: 64 K-steps, raw barrier + counted vmcnt (never 0) ----
    for (int t = 0; t < 64; ++t) {
        asm volatile("s_waitcnt vmcnt(2)" ::: "memory");   // glds(t) landed; A(t)x2 in flight
        __builtin_amdgcn_s_barrier();

        const char* bufc = smem + (t & 1) * WTILE_B;
        float4 na0, na1;
        if (t < 63) {
            char* bufn = smem + ((t + 1) & 1) * WTILE_B;
            const char* wt = Wpk + (size_t)(t + 1) * WTILE_B;
#pragma unroll
            for (int i = 0; i < 5; ++i) {
                const int task = tid + 512 * i;
                glds16(wt + (size_t)task * 16, bufn + task * 16);
            }
            __builtin_amdgcn_sched_barrier(0);             // keep glds before A-load (vmcnt order)
            const float* ap = aptr + (t + 1) * 16;
            na0 = *(const float4*)(ap);
            na1 = *(const float4*)(ap + 4);
        }
        __builtin_amdgcn_sched_barrier(0);                 // pin issue block above compute

        // convert A(t): 8 fp32 -> hi/lo bf16x8 (compiler inserts counted vmcnt for xa)
        union { float4 f[2]; float s[8]; } ua;
        ua.f[0] = xa0; ua.f[1] = xa1;
        union { short s[8]; bf16x8 v; } uh, ul;
#pragma unroll
        for (int e = 0; e < 8; ++e) {
            const short hb = f2bf(ua.s[e]);
            uh.s[e] = hb;
            ul.s[e] = f2bf(ua.s[e] - bf2f(hb));
        }
        const bf16x8 a_h = uh.v, a_l = ul.v;

        __builtin_amdgcn_s_setprio(1);
#pragma unroll
        for (int nt = 0; nt < 10; ++nt) {
            const int bcol = nw * 320 + nt * 32 + cl;
            const bf16x8 b_h = ld_frag((const short*)(bufc + bcol * 32 + h * 16));
            const bf16x8 b_l = ld_frag((const short*)(bufc + 20480 + bcol * 32 + h * 16));
            acc[nt] = __builtin_amdgcn_mfma_f32_32x32x16_bf16(a_h, b_h, acc[nt], 0, 0, 0);
            acc[nt] = __builtin_amdgcn_mfma_f32_32x32x16_bf16(a_l, b_h, acc[nt], 0, 0, 0);
            acc[nt] = __builtin_amdgcn_mfma_f32_32x32x16_bf16(a_h, b_l, acc[nt], 0, 0, 0);
        }
        __builtin_amdgcn_s_setprio(0);

        xa0 = na0; xa1 = na1;
    }

    // ---- epilogue (aliases buf0; all tile-62/63 LDS reads completed pre-barriers) ----
    float* psum_l = (float*)(smem);          // [640] f32
    int*   cnt_l  = (int*)(smem + 2560);     // [640] i32
    int*   gidx   = (int*)(smem + 5120);     // [128][2]

    for (int i = tid; i < GV; i += 512) { psum_l[i] = 0.f; cnt_l[i] = 0; }
    __syncthreads();

    // bias add (D layout 32x32: col = cl, row = (reg&3) + 8*(reg>>2) + 4*h)
#pragma unroll
    for (int nt = 0; nt < 10; ++nt) {
        const float bv = bias[nw * 320 + nt * 32 + cl];
#pragma unroll
        for (int r = 0; r < 16; ++r) acc[nt][r] += bv;
    }

    float pcol[10];
#pragma unroll
    for (int nt = 0; nt < 10; ++nt) pcol[nt] = 0.f;

#pragma unroll
    for (int reg = 0; reg < 16; ++reg) {
        const int rloc = mw * 32 + (reg & 3) + 8 * (reg >> 2) + 4 * h;
        const float* gp = gumbel + (size_t)(row0 + rloc) * GV + nw * 320;
        float bestv = -3.4e38f, gbv = -3.4e38f;
        int bestc = 0, gbc = 0;
#pragma unroll
        for (int nt = 0; nt < 10; ++nt) {
            const float v = acc[nt][reg];
            const int cc = nt * 32 + cl;
            const float tv = v + gp[cc];
            if (v > bestv) { bestv = v; bestc = cc; }
            if (tv > gbv)  { gbv = tv;  gbc = cc; }
        }
#pragma unroll
        for (int off = 1; off < 32; off <<= 1) {
            const float v2 = __shfl_xor(bestv, off); const int c2 = __shfl_xor(bestc, off);
            if (v2 > bestv || (v2 == bestv && c2 < bestc)) { bestv = v2; bestc = c2; }
            const float g2 = __shfl_xor(gbv, off); const int gc2 = __shfl_xor(gbc, off);
            if (g2 > gbv || (g2 == gbv && gc2 < gbc)) { gbv = g2; gbc = gc2; }
        }
        float e[10], s = 0.f;
#pragma unroll
        for (int nt = 0; nt < 10; ++nt) { e[nt] = __expf(acc[nt][reg] - bestv); s += e[nt]; }
#pragma unroll
        for (int off = 1; off < 32; off <<= 1) s += __shfl_xor(s, off);
        const float inv_s = 1.0f / s;
#pragma unroll
        for (int nt = 0; nt < 10; ++nt) pcol[nt] += e[nt] * inv_s;
        if (cl == 0) {
            atomicAdd(&cnt_l[nw * 320 + bestc], 1);
            gidx[rloc * 2 + nw] = nw * 320 + gbc;
        }
    }
#pragma unroll
    for (int nt = 0; nt < 10; ++nt) {
        const float v = pcol[nt] + __shfl_xor(pcol[nt], 32);
        if (h == 0) atomicAdd(&psum_l[nw * 320 + nt * 32 + cl], v);
    }
    __syncthreads();

    // q gather: 128 rows x 2 groups x 128 dims; 2 threads per (row,group)
    {
        const int unit = tid >> 1, half = tid & 1;
        const int row = unit >> 1, gq = unit & 1;
        const int idx = gidx[row * 2 + gq];
        const float4* srcp = (const float4*)(codebook + (size_t)idx * VD + half * 64);
        float4* dstp = (float4*)(q + (size_t)(row0 + row) * 256 + gq * VD + half * 64);
#pragma unroll
        for (int i = 0; i < 16; ++i) dstp[i] = srcp[i];
    }
    // flush block accumulators
    for (int i = tid; i < GV; i += 512) {
        atomicAdd(&psum_g[i], psum_l[i]);
        atomicAdd(&cnt_g[i], cnt_l[i]);
    }
}

// ---------- finalize ----------
__global__ void finalize(const int* __restrict__ cnt_g, const float* __restrict__ psum_g,
                         float* __restrict__ out_scalars)
{
    const int lane = threadIdx.x;   // 64 threads = 1 wave
    float hsum[2] = {0.f, 0.f}, p[2] = {0.f, 0.f};
    for (int i = lane; i < GV; i += 64) {
        const int g = i / NV;
        const float hp = (float)cnt_g[i] * INV_BT;
        const float ap = psum_g[i] * INV_BT;
        hsum[g] -= hp * logf(hp + 1e-7f);
        p[g]    -= ap * logf(ap + 1e-7f);
    }
#pragma unroll
    for (int off = 32; off > 0; off >>= 1) {
        hsum[0] += __shfl_xor(hsum[0], off); hsum[1] += __shfl_xor(hsum[1], off);
        p[0] += __shfl_xor(p[0], off);       p[1] += __shfl_xor(p[1], off);
    }
    if (lane == 0) {
        out_scalars[0] = expf(hsum[0]) + expf(hsum[1]);
        out_scalars[1] = expf(p[0]) + expf(p[1]);
    }
}

extern "C" void kernel_launch(void* const* d_in, const int* in_sizes, int n_in,
                              void* d_out, int out_size, void* d_ws, size_t ws_size,
                              hipStream_t stream)
{
    const float* X  = (const float*)d_in[0];   // [64000,1024]
    const float* W  = (const float*)d_in[1];   // [640,1024]
    const float* Bv = (const float*)d_in[2];   // [640]
    const float* CB = (const float*)d_in[3];   // [640,128]
    const float* GU = (const float*)d_in[4];   // [64000,640]

    float* q = (float*)d_out;                                  // [64000,256]
    float* out_scalars = (float*)d_out + (size_t)BT_TOT * 256; // 2 scalars

    char* ws = (char*)d_ws;
    float* psum_g = (float*)ws;                 // 640 floats
    int*   cnt_g  = (int*)(ws + 4096);          // 640 ints
    char*  Wpk    = ws + 8192;                  // 64 tiles * 40960 B = 2.62 MB

    prep<<<320, 256, 0, stream>>>(W, Wpk, psum_g, cnt_g);
    fused<<<500, 512, 0, stream>>>(X, Wpk, Bv, GU, CB, q, psum_g, cnt_g);
    finalize<<<1, 64, 0, stream>>>(cnt_g, psum_g, out_scalars);
}

// Round 4
// 706.939 us; speedup vs baseline: 1.0176x; 1.0176x over previous
//
#include <hip/hip_runtime.h>
#include <cstdint>
#include <cstddef>

#define BT_TOT 64000
#define FIN    1024
#define GV     640
#define NV     320
#define VD     128
#define INV_BT (1.0f/64000.0f)

// K-tile = 16. 64 K-steps. Wpk per kt: [g(2)][s(hi/lo)][320 cols x 2 chunks x 16B]
#define WTILE_B 40960
#define GTILE_B 20480

typedef __attribute__((ext_vector_type(8))) __bf16 bf16x8;
typedef __attribute__((ext_vector_type(16))) float f32x16;

typedef __attribute__((address_space(1))) void gvoid_t;
typedef __attribute__((address_space(3))) void lvoid_t;

__device__ inline short f2bf(float x) {            // RNE fp32 -> bf16 bits
    unsigned int u = __float_as_uint(x);
    unsigned int r = (u + 0x7fffu + ((u >> 16) & 1u)) >> 16;
    return (short)r;
}
__device__ inline float bf2f(short h) {
    return __uint_as_float(((unsigned int)(unsigned short)h) << 16);
}
__device__ inline bf16x8 ld_frag(const char* p) {
    union { uint4 u; bf16x8 v; } t;
    t.u = *(const uint4*)p;
    return t.v;
}
__device__ __forceinline__ void glds16(const void* g, void* l) {
    __builtin_amdgcn_global_load_lds((gvoid_t*)g, (lvoid_t*)l, 16, 0, 0);
}

// ---------- prep: split W into bf16 hi/lo, packed per-K-tile, linear ----------
__global__ __launch_bounds__(256) void prep(
    const float* __restrict__ W, char* __restrict__ Wpk,
    float* __restrict__ psum_g, int* __restrict__ cnt_g)
{
    const int t = blockIdx.x * 256 + threadIdx.x;
    if (t < GV) { psum_g[t] = 0.f; cnt_g[t] = 0; }
    const int r   = t >> 7;        // W row (out col) 0..639
    const int ck8 = t & 127;       // 8-elem chunk along k
    const int kt  = ck8 >> 1;      // K-tile 0..63
    const int chk = ck8 & 1;       // chunk within tile (0/1)
    const int g   = (r >= NV) ? 1 : 0;
    const int c   = r - g * NV;    // col within group 0..319
    const float* src = W + (size_t)r * FIN + (size_t)ck8 * 8;
    const float4 a = ((const float4*)src)[0];
    const float4 b = ((const float4*)src)[1];
    float xs[8] = {a.x, a.y, a.z, a.w, b.x, b.y, b.z, b.w};
    short hi[8], lo[8];
#pragma unroll
    for (int e = 0; e < 8; ++e) {
        hi[e] = f2bf(xs[e]);
        lo[e] = f2bf(xs[e] - bf2f(hi[e]));
    }
    const int u = c * 2 + chk;     // 16B-unit 0..639 within the group's hi region
    char* base = Wpk + (size_t)kt * WTILE_B + (size_t)g * GTILE_B;
    *(uint4*)(base + u * 16)         = *(uint4*)hi;   // hi: units 0..639
    *(uint4*)(base + 10240 + u * 16) = *(uint4*)lo;   // lo: units 640..1279
}

// ---------- fused: 32x32x16 bf16-triple GEMM, 16-wave blocks, 40 KB LDS ----------
// Grid 512 (500 active) x 1024 thr. Block = 256 rows x 320 cols (one group).
// 16 waves = 8 row-stripes x 2 col-halves; wave tile 32x160 = 5 x (32x32), acc 80.
// A global->reg; W staged via global_load_lds, 2 x 20 KB dbuf, counted vmcnt(2).
__global__ __launch_bounds__(1024, 4) void fused(
    const float* __restrict__ X, const char* __restrict__ Wpk,
    const float* __restrict__ bias, const float* __restrict__ gumbel,
    const float* __restrict__ codebook, float* __restrict__ q,
    float* __restrict__ psum_g, int* __restrict__ cnt_g)
{
    __shared__ __align__(16) char smem[2 * GTILE_B];   // 40 KB

    // XCD-aware swizzle; 12 idle blocks (block-uniform early exit, no barriers yet)
    const int id = blockIdx.x;
    const int linear = (id & 7) * 64 + (id >> 3);
    if (linear >= 500) return;
    const int rb = linear >> 1, g = linear & 1;

    const int tid  = threadIdx.x;
    const int lane = tid & 63, wave = tid >> 6;
    const int stripe = wave >> 1, ch = wave & 1;       // row-stripe, col-half
    const int cl = lane & 31, h = lane >> 5;
    const int row0 = rb * 256;
    const int arow = stripe * 32 + cl;                 // A row this lane owns

    const int u2 = 1024 + (tid & 255);                 // 2nd glds unit (dup-idempotent)
    const int rdbase = ch * 5120 + cl * 32 + h * 16;   // B-frag byte base in tile

    f32x16 acc[5];
#pragma unroll
    for (int nt = 0; nt < 5; ++nt) acc[nt] = (f32x16)0.0f;

    const float* aptr = X + (size_t)(row0 + arow) * FIN + h * 8;
    const char*  wbase = Wpk + (size_t)g * GTILE_B;

    // ---- prologue: stage K-tile 0 -> buf0, A(0) -> regs ----
    float4 xa0, xa1;
    {
        glds16(wbase + (size_t)tid * 16, smem + tid * 16);
        glds16(wbase + (size_t)u2 * 16,  smem + u2 * 16);
        __builtin_amdgcn_sched_barrier(0);
        xa0 = *(const float4*)(aptr);
        xa1 = *(const float4*)(aptr + 4);
    }

    // ---- main loop: 64 K-steps, raw barrier + counted vmcnt (never 0) ----
    for (int t = 0; t < 64; ++t) {
        asm volatile("s_waitcnt vmcnt(2)" ::: "memory");   // glds(t) landed; A(t)x2 in flight
        __builtin_amdgcn_s_barrier();
        __builtin_amdgcn_sched_barrier(0);

        const char* bufc = smem + (t & 1) * GTILE_B;
        if (t < 63) {
            char* bufn = smem + ((t + 1) & 1) * GTILE_B;
            const char* wt = wbase + (size_t)(t + 1) * WTILE_B;
            glds16(wt + (size_t)tid * 16, bufn + tid * 16);
            glds16(wt + (size_t)u2 * 16,  bufn + u2 * 16);
        }
        __builtin_amdgcn_sched_barrier(0);

        // convert A(t): 8 fp32 -> hi/lo bf16x8 (waits xa via counted vmcnt, in-order)
        union { float4 f[2]; float s[8]; } ua;
        ua.f[0] = xa0; ua.f[1] = xa1;
        union { short s[8]; bf16x8 v; } uh, ul;
#pragma unroll
        for (int e = 0; e < 8; ++e) {
            const short hb = f2bf(ua.s[e]);
            uh.s[e] = hb;
            ul.s[e] = f2bf(ua.s[e] - bf2f(hb));
        }
        const bf16x8 a_h = uh.v, a_l = ul.v;
        __builtin_amdgcn_sched_barrier(0);

        // reload A regs for t+1 (after convert consumed them; latency hides under MFMA)
        if (t < 63) {
            const float* ap = aptr + (t + 1) * 16;
            xa0 = *(const float4*)(ap);
            xa1 = *(const float4*)(ap + 4);
        }
        __builtin_amdgcn_sched_barrier(0);

        __builtin_amdgcn_s_setprio(1);
#pragma unroll
        for (int nt = 0; nt < 5; ++nt) {
            const bf16x8 b_h = ld_frag(bufc + nt * 1024 + rdbase);
            const bf16x8 b_l = ld_frag(bufc + 10240 + nt * 1024 + rdbase);
            acc[nt] = __builtin_amdgcn_mfma_f32_32x32x16_bf16(a_h, b_h, acc[nt], 0, 0, 0);
            acc[nt] = __builtin_amdgcn_mfma_f32_32x32x16_bf16(a_l, b_h, acc[nt], 0, 0, 0);
            acc[nt] = __builtin_amdgcn_mfma_f32_32x32x16_bf16(a_h, b_l, acc[nt], 0, 0, 0);
        }
        __builtin_amdgcn_s_setprio(0);
    }

    // ---- epilogue (LDS < 20480 B, disjoint from buf1 which step 63 read) ----
    float* psum_l = (float*)(smem);            // [320] f32   @0
    int*   cnt_l  = (int*)(smem + 1280);       // [320] i32   @1280
    int*   gidx   = (int*)(smem + 2560);       // [256]       @2560
    float* sv  = (float*)(smem + 4096);        // [512] local max      (row*2+ch)
    int*   sc  = (int*)(smem + 6144);          // [512] local argmax
    float* sgv = (float*)(smem + 8192);        // [512] local gumbel max
    int*   sgc = (int*)(smem + 10240);         // [512] local gumbel argmax
    float* ss  = (float*)(smem + 12288);       // [512] local exp-sum (vs local max)

    for (int i = tid; i < NV; i += 1024) { psum_l[i] = 0.f; cnt_l[i] = 0; }

    // bias add (D layout 32x32: col = cl, row = (reg&3) + 8*(reg>>2) + 4*h)
#pragma unroll
    for (int nt = 0; nt < 5; ++nt) {
        const float bv = bias[g * NV + ch * 160 + nt * 32 + cl];
#pragma unroll
        for (int r = 0; r < 16; ++r) acc[nt][r] += bv;
    }

    float pcol[5];
#pragma unroll
    for (int nt = 0; nt < 5; ++nt) pcol[nt] = 0.f;

#pragma unroll
    for (int c0 = 0; c0 < 16; c0 += 4) {
        float bv[4], gv[4], sl[4];
        int bc[4], gc[4];
        // phase 1: local (this col-half) max/argmax + exp-sum vs local max
#pragma unroll
        for (int j = 0; j < 4; ++j) {
            const int reg = c0 + j;
            const int rloc = stripe * 32 + (reg & 3) + 8 * (reg >> 2) + 4 * h;
            const float* gp = gumbel + (size_t)(row0 + rloc) * GV + g * NV;
            float bestv = -3.4e38f, gbv = -3.4e38f;
            int bestc = 0, gbc = 0;
#pragma unroll
            for (int nt = 0; nt < 5; ++nt) {
                const float v = acc[nt][reg];
                const int cc = ch * 160 + nt * 32 + cl;
                const float tv = v + gp[cc];
                if (v > bestv) { bestv = v; bestc = cc; }
                if (tv > gbv)  { gbv = tv;  gbc = cc; }
            }
#pragma unroll
            for (int off = 1; off < 32; off <<= 1) {
                const float v2 = __shfl_xor(bestv, off); const int c2 = __shfl_xor(bestc, off);
                if (v2 > bestv || (v2 == bestv && c2 < bestc)) { bestv = v2; bestc = c2; }
                const float g2 = __shfl_xor(gbv, off); const int gc2 = __shfl_xor(gbc, off);
                if (g2 > gbv || (g2 == gbv && gc2 < gbc)) { gbv = g2; gbc = gc2; }
            }
            float s = 0.f;
#pragma unroll
            for (int nt = 0; nt < 5; ++nt) s += __expf(acc[nt][reg] - bestv);
#pragma unroll
            for (int off = 1; off < 32; off <<= 1) s += __shfl_xor(s, off);
            bv[j] = bestv; bc[j] = bestc; gv[j] = gbv; gc[j] = gbc; sl[j] = s;
            if (cl == 0) {
                const int si = rloc * 2 + ch;
                sv[si] = bestv; sc[si] = bestc; sgv[si] = gbv; sgc[si] = gbc; ss[si] = s;
            }
        }
        __syncthreads();
        // phase 2: merge with partner col-half (online-softmax combine)
#pragma unroll
        for (int j = 0; j < 4; ++j) {
            const int reg = c0 + j;
            const int rloc = stripe * 32 + (reg & 3) + 8 * (reg >> 2) + 4 * h;
            const int pi = rloc * 2 + (ch ^ 1);
            const float pv = sv[pi]; const int pc = sc[pi];
            const float pgv = sgv[pi]; const int pgc = sgc[pi];
            const float ps = ss[pi];
            float m = bv[j]; int mc = bc[j];
            if (pv > m || (pv == m && pc < mc)) { m = pv; mc = pc; }
            float mg = gv[j]; int mgc = gc[j];
            if (pgv > mg || (pgv == mg && pgc < mgc)) { mg = pgv; mgc = pgc; }
            const float fl = __expf(bv[j] - m);
            const float stot = sl[j] * fl + ps * __expf(pv - m);
            const float fscale = fl / stot;
#pragma unroll
            for (int nt = 0; nt < 5; ++nt)
                pcol[nt] += __expf(acc[nt][reg] - bv[j]) * fscale;
            if (ch == 0 && cl == 0) {
                atomicAdd(&cnt_l[mc], 1);
                gidx[rloc] = mgc;
            }
        }
    }

    // fold column sums over h, then into block accumulator (per-half cols disjoint)
#pragma unroll
    for (int nt = 0; nt < 5; ++nt) {
        const float v = pcol[nt] + __shfl_xor(pcol[nt], 32);
        if (h == 0) atomicAdd(&psum_l[ch * 160 + nt * 32 + cl], v);
    }
    __syncthreads();

    // q gather: 256 rows x 128 dims (this block's group); 4 threads per row
    {
        const int row = tid >> 2, quarter = tid & 3;
        const int idx = g * NV + gidx[row];
        const float4* srcp = (const float4*)(codebook + (size_t)idx * VD + quarter * 32);
        float4* dstp = (float4*)(q + (size_t)(row0 + row) * 256 + g * VD + quarter * 32);
#pragma unroll
        for (int i = 0; i < 8; ++i) dstp[i] = srcp[i];
    }
    // flush block accumulators
    for (int i = tid; i < NV; i += 1024) {
        atomicAdd(&psum_g[g * NV + i], psum_l[i]);
        atomicAdd(&cnt_g[g * NV + i], cnt_l[i]);
    }
}

// ---------- finalize ----------
__global__ void finalize(const int* __restrict__ cnt_g, const float* __restrict__ psum_g,
                         float* __restrict__ out_scalars)
{
    const int lane = threadIdx.x;   // 64 threads = 1 wave
    float hsum[2] = {0.f, 0.f}, p[2] = {0.f, 0.f};
    for (int i = lane; i < GV; i += 64) {
        const int g = i / NV;
        const float hp = (float)cnt_g[i] * INV_BT;
        const float ap = psum_g[i] * INV_BT;
        hsum[g] -= hp * logf(hp + 1e-7f);
        p[g]    -= ap * logf(ap + 1e-7f);
    }
#pragma unroll
    for (int off = 32; off > 0; off >>= 1) {
        hsum[0] += __shfl_xor(hsum[0], off); hsum[1] += __shfl_xor(hsum[1], off);
        p[0] += __shfl_xor(p[0], off);       p[1] += __shfl_xor(p[1], off);
    }
    if (lane == 0) {
        out_scalars[0] = expf(hsum[0]) + expf(hsum[1]);
        out_scalars[1] = expf(p[0]) + expf(p[1]);
    }
}

extern "C" void kernel_launch(void* const* d_in, const int* in_sizes, int n_in,
                              void* d_out, int out_size, void* d_ws, size_t ws_size,
                              hipStream_t stream)
{
    const float* X  = (const float*)d_in[0];   // [64000,1024]
    const float* W  = (const float*)d_in[1];   // [640,1024]
    const float* Bv = (const float*)d_in[2];   // [640]
    const float* CB = (const float*)d_in[3];   // [640,128]
    const float* GU = (const float*)d_in[4];   // [64000,640]

    float* q = (float*)d_out;                                  // [64000,256]
    float* out_scalars = (float*)d_out + (size_t)BT_TOT * 256; // 2 scalars

    char* ws = (char*)d_ws;
    float* psum_g = (float*)ws;                 // 640 floats
    int*   cnt_g  = (int*)(ws + 4096);          // 640 ints
    char*  Wpk    = ws + 8192;                  // 64 tiles * 40960 B = 2.62 MB

    prep<<<320, 256, 0, stream>>>(W, Wpk, psum_g, cnt_g);
    fused<<<512, 1024, 0, stream>>>(X, Wpk, Bv, GU, CB, q, psum_g, cnt_g);
    finalize<<<1, 64, 0, stream>>>(cnt_g, psum_g, out_scalars);
}

// Round 5
// 664.128 us; speedup vs baseline: 1.0832x; 1.0645x over previous
//
#include <hip/hip_runtime.h>
#include <cstdint>
#include <cstddef>

#define BT_TOT 64000
#define FIN    1024
#define GV     640
#define NV     320
#define VD     128
#define INV_BT (1.0f/64000.0f)

// Iteration = BK 32 (2 chunks of 16). 32 iterations.
// Wpk layout: [iter(32)][g(2)][chunk(2)][s(hi/lo)][320 cols x 2 k-halves x 16B]
//   per (iter,g): contiguous 81920/2 = 40960 B -> linear global_load_lds staging.
#define ITER_B  81920
#define BUF_B   40960

typedef __attribute__((ext_vector_type(8))) __bf16 bf16x8;
typedef __attribute__((ext_vector_type(16))) float f32x16;

typedef __attribute__((address_space(1))) void gvoid_t;
typedef __attribute__((address_space(3))) void lvoid_t;

__device__ inline short f2bf(float x) {            // RNE fp32 -> bf16 bits
    unsigned int u = __float_as_uint(x);
    unsigned int r = (u + 0x7fffu + ((u >> 16) & 1u)) >> 16;
    return (short)r;
}
__device__ inline float bf2f(short h) {
    return __uint_as_float(((unsigned int)(unsigned short)h) << 16);
}
__device__ inline bf16x8 ld_frag(const char* p) {
    union { uint4 u; bf16x8 v; } t;
    t.u = *(const uint4*)p;
    return t.v;
}
__device__ __forceinline__ void glds16(const void* g, void* l) {
    __builtin_amdgcn_global_load_lds((gvoid_t*)g, (lvoid_t*)l, 16, 0, 0);
}
__device__ __forceinline__ void cvt8(const float4 f0, const float4 f1,
                                     bf16x8& hh, bf16x8& ll) {
    union { float4 f[2]; float s[8]; } ua; ua.f[0] = f0; ua.f[1] = f1;
    union { short s[8]; bf16x8 v; } uh, ul;
#pragma unroll
    for (int e = 0; e < 8; ++e) {
        const short hb = f2bf(ua.s[e]);
        uh.s[e] = hb;
        ul.s[e] = f2bf(ua.s[e] - bf2f(hb));
    }
    hh = uh.v; ll = ul.v;
}

// ---------- prep: split W into bf16 hi/lo, packed per-iteration ----------
__global__ __launch_bounds__(256) void prep(
    const float* __restrict__ W, char* __restrict__ Wpk,
    float* __restrict__ psum_g, int* __restrict__ cnt_g)
{
    const int t = blockIdx.x * 256 + threadIdx.x;
    if (t < GV) { psum_g[t] = 0.f; cnt_g[t] = 0; }
    const int r    = t >> 7;        // W row (out col) 0..639
    const int ck8  = t & 127;       // 8-elem chunk along k
    const int iter = ck8 >> 2;      // iteration 0..31
    const int c    = (ck8 >> 1) & 1;// chunk within iteration
    const int ch   = ck8 & 1;       // k-half within chunk (h)
    const int g    = (r >= NV) ? 1 : 0;
    const int cv   = r - g * NV;    // col within group 0..319
    const float* src = W + (size_t)r * FIN + (size_t)ck8 * 8;
    const float4 a = ((const float4*)src)[0];
    const float4 b = ((const float4*)src)[1];
    float xs[8] = {a.x, a.y, a.z, a.w, b.x, b.y, b.z, b.w};
    short hi[8], lo[8];
#pragma unroll
    for (int e = 0; e < 8; ++e) {
        hi[e] = f2bf(xs[e]);
        lo[e] = f2bf(xs[e] - bf2f(hi[e]));
    }
    char* dst = Wpk + (size_t)iter * ITER_B + (size_t)g * BUF_B + (size_t)c * 20480
                    + (size_t)(cv * 32 + ch * 16);
    *(uint4*)dst           = *(uint4*)hi;   // s=0 (hi)
    *(uint4*)(dst + 10240) = *(uint4*)lo;   // s=1 (lo)
}

// ---------- fused: 32x32x16 bf16-triple GEMM, 8-phase-rhythm pipeline ----------
// Grid 512 (500 active) x 512 thr. Block = 256 rows x 320 cols (one group).
// 8 waves = 8 row-stripes of 32; wave tile 32x320 = 10 x (32x32), acc 160.
// Per iteration (BK=32): 4 phases, each {10 ds_read + stage-issue | barrier |
// lgkmcnt(0) | 15 MFMA (setprio) | barrier}; staging vmcnt counted, never drained.
__global__ __launch_bounds__(512) void fused(
    const float* __restrict__ X, const char* __restrict__ Wpk,
    const float* __restrict__ bias, const float* __restrict__ gumbel,
    const float* __restrict__ codebook, float* __restrict__ q,
    float* __restrict__ psum_g, int* __restrict__ cnt_g)
{
    __shared__ __align__(16) char smem[2 * BUF_B];   // 80 KB

    // XCD-aware swizzle: (rb, g=0/1) pair lands on same XCD; 12 inert blocks.
    const int id = blockIdx.x;
    const int linear = (id & 7) * 64 + (id >> 3);
    if (linear >= 500) return;
    const int rb = linear >> 1, g = linear & 1;

    const int tid  = threadIdx.x;
    const int lane = tid & 63, wave = tid >> 6;
    const int cl = lane & 31, h = lane >> 5;
    const int row0 = rb * 256;
    const int arow = wave * 32 + cl;                  // A row this lane owns
    const int rdo  = cl * 32 + h * 16;                // frag byte offset in s-region

    f32x16 acc[10];
#pragma unroll
    for (int nt = 0; nt < 10; ++nt) acc[nt] = (f32x16)0.0f;

    const float* aptr  = X + (size_t)(row0 + arow) * FIN + h * 8;
    const char*  wbase = Wpk + (size_t)g * BUF_B;

    // ---- prologue: stage iter 0 -> buf0, A(iter0 chunk0/1) -> regs ----
    float4 xa0, xa1, xa2, xa3;
    {
#pragma unroll
        for (int j = 0; j < 5; ++j)
            glds16(wbase + (size_t)(tid + 512 * j) * 16, smem + (tid + 512 * j) * 16);
        __builtin_amdgcn_sched_barrier(0);
        xa0 = *(const float4*)(aptr);
        xa1 = *(const float4*)(aptr + 4);
        xa2 = *(const float4*)(aptr + 16);
        xa3 = *(const float4*)(aptr + 20);
        asm volatile("s_waitcnt vmcnt(4)" ::: "memory");   // glds done; 4 A-loads in flight
        __builtin_amdgcn_s_barrier();
    }

    // ---- main loop: 32 iterations x 4 phases ----
    for (int i = 0; i < 32; ++i) {
        const char* bufc = smem + (i & 1) * BUF_B;
        char* bufn = smem + ((i + 1) & 1) * BUF_B;
        const char* wsrc = wbase + (size_t)(i + 1) * ITER_B;
        const float* apn = aptr + (i + 1) * 32;
        const bool more = (i < 31);
        bf16x8 bh[5], bl[5], ah, al;

        // ================= phase 0: chunk0, nt 0..4 =================
#pragma unroll
        for (int n = 0; n < 5; ++n) {
            bh[n] = ld_frag(bufc + n * 1024 + rdo);
            bl[n] = ld_frag(bufc + 10240 + n * 1024 + rdo);
        }
        if (more) {
            glds16(wsrc + (size_t)tid * 16,         bufn + tid * 16);
            glds16(wsrc + (size_t)(tid + 512) * 16, bufn + (tid + 512) * 16);
        }
        cvt8(xa0, xa1, ah, al);                       // chunk0 (compiler waits A-loads)
        __builtin_amdgcn_sched_barrier(0);
        __builtin_amdgcn_s_barrier();
        asm volatile("s_waitcnt lgkmcnt(0)" ::: "memory");
        __builtin_amdgcn_sched_barrier(0);
        __builtin_amdgcn_s_setprio(1);
#pragma unroll
        for (int n = 0; n < 5; ++n) {
            acc[n] = __builtin_amdgcn_mfma_f32_32x32x16_bf16(ah, bh[n], acc[n], 0, 0, 0);
            acc[n] = __builtin_amdgcn_mfma_f32_32x32x16_bf16(al, bh[n], acc[n], 0, 0, 0);
            acc[n] = __builtin_amdgcn_mfma_f32_32x32x16_bf16(ah, bl[n], acc[n], 0, 0, 0);
        }
        __builtin_amdgcn_s_setprio(0);
        __builtin_amdgcn_s_barrier();

        // ================= phase 1: chunk0, nt 5..9 =================
#pragma unroll
        for (int n = 0; n < 5; ++n) {
            bh[n] = ld_frag(bufc + (n + 5) * 1024 + rdo);
            bl[n] = ld_frag(bufc + 10240 + (n + 5) * 1024 + rdo);
        }
        if (more)
            glds16(wsrc + (size_t)(tid + 1024) * 16, bufn + (tid + 1024) * 16);
        __builtin_amdgcn_sched_barrier(0);
        __builtin_amdgcn_s_barrier();
        asm volatile("s_waitcnt lgkmcnt(0)" ::: "memory");
        __builtin_amdgcn_sched_barrier(0);
        __builtin_amdgcn_s_setprio(1);
#pragma unroll
        for (int n = 0; n < 5; ++n) {
            acc[n + 5] = __builtin_amdgcn_mfma_f32_32x32x16_bf16(ah, bh[n], acc[n + 5], 0, 0, 0);
            acc[n + 5] = __builtin_amdgcn_mfma_f32_32x32x16_bf16(al, bh[n], acc[n + 5], 0, 0, 0);
            acc[n + 5] = __builtin_amdgcn_mfma_f32_32x32x16_bf16(ah, bl[n], acc[n + 5], 0, 0, 0);
        }
        __builtin_amdgcn_s_setprio(0);
        __builtin_amdgcn_s_barrier();

        // ================= phase 2: chunk1, nt 0..4 =================
#pragma unroll
        for (int n = 0; n < 5; ++n) {
            bh[n] = ld_frag(bufc + 20480 + n * 1024 + rdo);
            bl[n] = ld_frag(bufc + 30720 + n * 1024 + rdo);
        }
        if (more) {
            glds16(wsrc + (size_t)(tid + 1536) * 16, bufn + (tid + 1536) * 16);
            __builtin_amdgcn_sched_barrier(0);         // keep glds before A-loads
            xa0 = *(const float4*)(apn);
            xa1 = *(const float4*)(apn + 4);
        }
        cvt8(xa2, xa3, ah, al);                       // chunk1
        __builtin_amdgcn_sched_barrier(0);
        __builtin_amdgcn_s_barrier();
        asm volatile("s_waitcnt lgkmcnt(0)" ::: "memory");
        __builtin_amdgcn_sched_barrier(0);
        __builtin_amdgcn_s_setprio(1);
#pragma unroll
        for (int n = 0; n < 5; ++n) {
            acc[n] = __builtin_amdgcn_mfma_f32_32x32x16_bf16(ah, bh[n], acc[n], 0, 0, 0);
            acc[n] = __builtin_amdgcn_mfma_f32_32x32x16_bf16(al, bh[n], acc[n], 0, 0, 0);
            acc[n] = __builtin_amdgcn_mfma_f32_32x32x16_bf16(ah, bl[n], acc[n], 0, 0, 0);
        }
        __builtin_amdgcn_s_setprio(0);
        __builtin_amdgcn_s_barrier();

        // ================= phase 3: chunk1, nt 5..9 =================
#pragma unroll
        for (int n = 0; n < 5; ++n) {
            bh[n] = ld_frag(bufc + 20480 + (n + 5) * 1024 + rdo);
            bl[n] = ld_frag(bufc + 30720 + (n + 5) * 1024 + rdo);
        }
        if (more) {
            glds16(wsrc + (size_t)(tid + 2048) * 16, bufn + (tid + 2048) * 16);
            __builtin_amdgcn_sched_barrier(0);         // keep glds before A-loads
            xa2 = *(const float4*)(apn + 16);
            xa3 = *(const float4*)(apn + 20);
        }
        __builtin_amdgcn_sched_barrier(0);
        __builtin_amdgcn_s_barrier();
        asm volatile("s_waitcnt lgkmcnt(0)" ::: "memory");
        __builtin_amdgcn_sched_barrier(0);
        __builtin_amdgcn_s_setprio(1);
#pragma unroll
        for (int n = 0; n < 5; ++n) {
            acc[n + 5] = __builtin_amdgcn_mfma_f32_32x32x16_bf16(ah, bh[n], acc[n + 5], 0, 0, 0);
            acc[n + 5] = __builtin_amdgcn_mfma_f32_32x32x16_bf16(al, bh[n], acc[n + 5], 0, 0, 0);
            acc[n + 5] = __builtin_amdgcn_mfma_f32_32x32x16_bf16(ah, bl[n], acc[n + 5], 0, 0, 0);
        }
        __builtin_amdgcn_s_setprio(0);
        // next buffer fully staged? (5 glds done; <=2 A-loads may remain in flight)
        asm volatile("s_waitcnt vmcnt(2)" ::: "memory");
        __builtin_amdgcn_s_barrier();
    }

    // ---- epilogue (aliases buf0; iter 31 computed from buf1) ----
    float* psum_l = (float*)(smem);          // [320] f32
    int*   cnt_l  = (int*)(smem + 1280);     // [320] i32
    int*   gidx   = (int*)(smem + 2560);     // [256]

    for (int i = tid; i < NV; i += 512) { psum_l[i] = 0.f; cnt_l[i] = 0; }
    __syncthreads();

    // bias add (D layout 32x32: col = cl, row = (reg&3) + 8*(reg>>2) + 4*h)
#pragma unroll
    for (int nt = 0; nt < 10; ++nt) {
        const float bv = bias[g * NV + nt * 32 + cl];
#pragma unroll
        for (int r = 0; r < 16; ++r) acc[nt][r] += bv;
    }

    float pcol[10];
#pragma unroll
    for (int nt = 0; nt < 10; ++nt) pcol[nt] = 0.f;

#pragma unroll
    for (int reg = 0; reg < 16; ++reg) {
        const int rloc = wave * 32 + (reg & 3) + 8 * (reg >> 2) + 4 * h;
        const float* gp = gumbel + (size_t)(row0 + rloc) * GV + g * NV;
        float bestv = -3.4e38f, gbv = -3.4e38f;
        int bestc = 0, gbc = 0;
#pragma unroll
        for (int nt = 0; nt < 10; ++nt) {
            const float v = acc[nt][reg];
            const int cc = nt * 32 + cl;
            const float tv = v + gp[cc];
            if (v > bestv) { bestv = v; bestc = cc; }
            if (tv > gbv)  { gbv = tv;  gbc = cc; }
        }
#pragma unroll
        for (int off = 1; off < 32; off <<= 1) {
            const float v2 = __shfl_xor(bestv, off); const int c2 = __shfl_xor(bestc, off);
            if (v2 > bestv || (v2 == bestv && c2 < bestc)) { bestv = v2; bestc = c2; }
            const float g2 = __shfl_xor(gbv, off); const int gc2 = __shfl_xor(gbc, off);
            if (g2 > gbv || (g2 == gbv && gc2 < gbc)) { gbv = g2; gbc = gc2; }
        }
        float e[10], s = 0.f;
#pragma unroll
        for (int nt = 0; nt < 10; ++nt) { e[nt] = __expf(acc[nt][reg] - bestv); s += e[nt]; }
#pragma unroll
        for (int off = 1; off < 32; off <<= 1) s += __shfl_xor(s, off);
        const float inv_s = 1.0f / s;
#pragma unroll
        for (int nt = 0; nt < 10; ++nt) pcol[nt] += e[nt] * inv_s;
        if (cl == 0) {
            atomicAdd(&cnt_l[bestc], 1);
            gidx[rloc] = gbc;
        }
    }
#pragma unroll
    for (int nt = 0; nt < 10; ++nt) {
        const float v = pcol[nt] + __shfl_xor(pcol[nt], 32);
        if (h == 0) atomicAdd(&psum_l[nt * 32 + cl], v);
    }
    __syncthreads();

    // q gather: 256 rows x 128 dims (this block's group); 2 threads per row
    {
        const int row = tid >> 1, half = tid & 1;
        const int idx = g * NV + gidx[row];
        const float4* srcp = (const float4*)(codebook + (size_t)idx * VD + half * 64);
        float4* dstp = (float4*)(q + (size_t)(row0 + row) * 256 + g * VD + half * 64);
#pragma unroll
        for (int i = 0; i < 16; ++i) dstp[i] = srcp[i];
    }
    // flush block accumulators
    for (int i = tid; i < NV; i += 512) {
        atomicAdd(&psum_g[g * NV + i], psum_l[i]);
        atomicAdd(&cnt_g[g * NV + i], cnt_l[i]);
    }
}

// ---------- finalize ----------
__global__ void finalize(const int* __restrict__ cnt_g, const float* __restrict__ psum_g,
                         float* __restrict__ out_scalars)
{
    const int lane = threadIdx.x;   // 64 threads = 1 wave
    float hsum[2] = {0.f, 0.f}, p[2] = {0.f, 0.f};
    for (int i = lane; i < GV; i += 64) {
        const int g = i / NV;
        const float hp = (float)cnt_g[i] * INV_BT;
        const float ap = psum_g[i] * INV_BT;
        hsum[g] -= hp * logf(hp + 1e-7f);
        p[g]    -= ap * logf(ap + 1e-7f);
    }
#pragma unroll
    for (int off = 32; off > 0; off >>= 1) {
        hsum[0] += __shfl_xor(hsum[0], off); hsum[1] += __shfl_xor(hsum[1], off);
        p[0] += __shfl_xor(p[0], off);       p[1] += __shfl_xor(p[1], off);
    }
    if (lane == 0) {
        out_scalars[0] = expf(hsum[0]) + expf(hsum[1]);
        out_scalars[1] = expf(p[0]) + expf(p[1]);
    }
}

extern "C" void kernel_launch(void* const* d_in, const int* in_sizes, int n_in,
                              void* d_out, int out_size, void* d_ws, size_t ws_size,
                              hipStream_t stream)
{
    const float* X  = (const float*)d_in[0];   // [64000,1024]
    const float* W  = (const float*)d_in[1];   // [640,1024]
    const float* Bv = (const float*)d_in[2];   // [640]
    const float* CB = (const float*)d_in[3];   // [640,128]
    const float* GU = (const float*)d_in[4];   // [64000,640]

    float* q = (float*)d_out;                                  // [64000,256]
    float* out_scalars = (float*)d_out + (size_t)BT_TOT * 256; // 2 scalars

    char* ws = (char*)d_ws;
    float* psum_g = (float*)ws;                 // 640 floats
    int*   cnt_g  = (int*)(ws + 4096);          // 640 ints
    char*  Wpk    = ws + 8192;                  // 32 iters * 81920 B = 2.62 MB

    prep<<<320, 256, 0, stream>>>(W, Wpk, psum_g, cnt_g);
    fused<<<512, 512, 0, stream>>>(X, Wpk, Bv, GU, CB, q, psum_g, cnt_g);
    finalize<<<1, 64, 0, stream>>>(cnt_g, psum_g, out_scalars);
}